// Round 1
// baseline (558.370 us; speedup 1.0000x reference)
//
#include <hip/hip_runtime.h>
#include <math.h>

#define DEV __device__ __forceinline__

constexpr int DI = 192, Nn = 16, Rr = 6;
constexpr int Cc = 96;
constexpr int Ll = 4096;           // 64*64
constexpr int NC = 64;             // scan chunks of 64 steps

DEV float silu_(float x) { return x / (1.f + __expf(-x)); }
DEV float wsum64(float v) {
  #pragma unroll
  for (int m = 32; m; m >>= 1) v += __shfl_xor(v, m, 64);
  return v;
}

// ---------------- LN over C=96 (wave per pixel) ----------------
__global__ void ln1_kernel(const float* __restrict__ x, const float* __restrict__ g,
                           const float* __restrict__ bt, float* __restrict__ xn) {
  int lane = threadIdx.x & 63;
  int pix = blockIdx.x * 4 + (threadIdx.x >> 6);
  const float* row = x + (size_t)pix * Cc;
  float v0 = row[lane];
  float v1 = (lane < 32) ? row[lane + 64] : 0.f;
  float s = wsum64(v0 + v1);
  float m = s * (1.f / 96.f);
  float q = wsum64(v0 * v0 + v1 * v1);
  float rs = rsqrtf(q * (1.f / 96.f) - m * m + 1e-6f);
  float* o = xn + (size_t)pix * Cc;
  o[lane] = (v0 - m) * rs * g[lane] + bt[lane];
  if (lane < 32) o[lane + 64] = (v1 - m) * rs * g[lane + 64] + bt[lane + 64];
}

// ---------------- generic 1x1 conv (GEMM over channels) ----------------
// IN_MODE: 0 = pixel-major [gp*CIN+c], 1 = channel-major [(b*CIN+c)*4096+p]
// OUT_MODE: 0 = pixel-major, 1 = channel-major, 2 = split xz (out=xx raw, out2=silu(z))
template<int CIN, int COUT, int IN_MODE, int OUT_MODE, int ACT, int HAS_BIAS>
__global__ void conv1x1_kernel(const float* __restrict__ in, const float* __restrict__ w,
                               const float* __restrict__ bias, float* __restrict__ out,
                               float* __restrict__ out2) {
  __shared__ float s_in[16][CIN + 1];
  int tid = threadIdx.x;
  int pbase = blockIdx.x * 16;
  for (int idx = tid; idx < 16 * CIN; idx += 256) {
    int px = idx / CIN, cc = idx - px * CIN;
    int gp = pbase + px;
    float v;
    if (IN_MODE == 0) v = in[(size_t)gp * CIN + cc];
    else { int b = gp >> 12, p = gp & 4095; v = in[((size_t)b * CIN + cc) * Ll + p]; }
    s_in[px][cc] = v;
  }
  __syncthreads();
  int px = tid & 15, og = tid >> 4;
  int gp = pbase + px;
  for (int oc = og; oc < COUT; oc += 16) {
    float acc = HAS_BIAS ? bias[oc] : 0.f;
    const float* wr = w + (size_t)oc * CIN;
    #pragma unroll 8
    for (int c = 0; c < CIN; ++c) acc += s_in[px][c] * wr[c];
    if (OUT_MODE == 2) {
      if (oc < 192) out[(size_t)gp * 192 + oc] = acc;
      else out2[(size_t)gp * 192 + (oc - 192)] = silu_(acc);
    } else {
      if (ACT == 1) acc = silu_(acc);
      if (OUT_MODE == 0) out[(size_t)gp * COUT + oc] = acc;
      else { int b = gp >> 12, p = gp & 4095; out[((size_t)b * COUT + oc) * Ll + p] = acc; }
    }
  }
}

// ---------------- depthwise 3x3 + bias + silu (NHWC, 192 ch) ----------------
__global__ void dwconv3_silu_kernel(const float* __restrict__ xx, const float* __restrict__ w,
                                    const float* __restrict__ bias, float* __restrict__ xc) {
  int idx = blockIdx.x * 256 + threadIdx.x;   // (b*L+p)*DI + d
  int d = idx % DI;
  int p = (idx / DI) & (Ll - 1);
  int b = idx / (DI * Ll);
  int h = p >> 6, wq = p & 63;
  const float* base = xx + (size_t)b * Ll * DI + d;
  const float* wr = w + d * 9;
  float acc = bias[d];
  #pragma unroll
  for (int i = 0; i < 3; ++i) {
    int hh = h - 1 + i;
    if ((unsigned)hh >= 64u) continue;
    #pragma unroll
    for (int j = 0; j < 3; ++j) {
      int ww2 = wq - 1 + j;
      if ((unsigned)ww2 >= 64u) continue;
      acc += base[(size_t)(hh * 64 + ww2) * DI] * wr[i * 3 + j];
    }
  }
  xc[idx] = silu_(acc);
}

// ---------------- x_proj + dt_proj + softplus (per (b,k,l)) ----------------
__global__ void proj_kernel(const float* __restrict__ xc, const float* __restrict__ xpw,
                            const float* __restrict__ dtw, const float* __restrict__ dtb,
                            float* __restrict__ BSo, float* __restrict__ CSo,
                            float* __restrict__ DTo) {
  __shared__ float xv[64][193];
  __shared__ float dts[64][9];
  int tid = threadIdx.x;
  int lane = tid & 63, wv = tid >> 6;
  int lb = (blockIdx.x & 63) * 64;
  int k = (blockIdx.x >> 6) & 3;
  int b = blockIdx.x >> 8;
  int bk = b * 4 + k;
  for (int it = wv; it < 64; it += 4) {
    int l = lb + it;
    int p;
    if (k == 0) p = l;
    else if (k == 1) p = ((l & 63) << 6) | (l >> 6);
    else if (k == 2) p = 4095 - l;
    else { int lr = 4095 - l; p = ((lr & 63) << 6) | (lr >> 6); }
    const float* src = xc + ((size_t)b * Ll + p) * DI;
    xv[it][lane]       = src[lane];
    xv[it][lane + 64]  = src[lane + 64];
    xv[it][lane + 128] = src[lane + 128];
  }
  __syncthreads();
  int i = lane, cg = wv;
  int l = lb + i;
  for (int c = cg; c < 38; c += 4) {
    const float* wr = xpw + ((size_t)k * 38 + c) * DI;
    float acc = 0.f;
    #pragma unroll 8
    for (int j = 0; j < DI; ++j) acc += xv[i][j] * wr[j];
    if (c < 6) dts[i][c] = acc;
    else if (c < 22) BSo[((size_t)bk * Ll + l) * Nn + (c - 6)] = acc;
    else             CSo[((size_t)bk * Ll + l) * Nn + (c - 22)] = acc;
  }
  __syncthreads();
  for (int d = cg; d < DI; d += 4) {
    float acc = dtb[k * DI + d];
    const float* wr = dtw + ((size_t)k * DI + d) * Rr;
    #pragma unroll
    for (int r = 0; r < Rr; ++r) acc += dts[i][r] * wr[r];
    float sp = (acc > 20.f) ? acc : log1pf(__expf(acc));
    DTo[((size_t)bk * DI + d) * Ll + l] = sp;
  }
}

// ---------------- scan helpers: direction start/stride within chunk ----------------
DEV void dir_p0_dp(int k, int c, int& p0, int& dp) {
  if (k == 0) { p0 = c * 64; dp = 1; }
  else if (k == 1) { p0 = c; dp = 64; }
  else if (k == 2) { p0 = 4095 - c * 64; dp = -1; }
  else { p0 = 4095 - c; dp = -64; }
}

// ---------------- scan pass A: per-chunk (prod a, partial) ----------------
__global__ void scanA_kernel(const float* __restrict__ dtg, const float* __restrict__ xc,
                             const float* __restrict__ bsg, const float* __restrict__ alog,
                             float* __restrict__ P, float* __restrict__ Q) {
  int g = blockIdx.x * 256 + threadIdx.x;   // ((bk*64+c)*192+d)*16+n
  int n = g & 15;
  int t1 = g >> 4;
  int d = t1 % DI;
  int t2 = t1 / DI;
  int c = t2 & 63;
  int bk = t2 >> 6;
  int k = bk & 3, b = bk >> 2;
  float An = -__expf(alog[(k * DI + d) * Nn + n]);
  const float* dtp = dtg + ((size_t)bk * DI + d) * Ll + c * 64;
  const float* bsp = bsg + ((size_t)bk * Ll + c * 64) * Nn + n;
  int p0, dp; dir_p0_dp(k, c, p0, dp);
  const float* up = xc + ((size_t)b * Ll + p0) * DI + d;
  int ustep = dp * DI;
  float Pv = 1.f, Qv = 0.f;
  #pragma unroll 4
  for (int t = 0; t < 64; ++t) {
    float dtv = dtp[t];
    float u = *up; up += ustep;
    float Bv = *bsp; bsp += Nn;
    float a = __expf(dtv * An);
    Pv *= a;
    Qv = Qv * a + dtv * u * Bv;
  }
  P[g] = Pv; Q[g] = Qv;
}

// ---------------- scan pass B: cross-chunk prefix ----------------
__global__ void scanB_kernel(const float* __restrict__ P, const float* __restrict__ Q,
                             float* __restrict__ H0) {
  int g = blockIdx.x * 256 + threadIdx.x;   // (bk*192+d)*16+n, 24576
  int n = g & 15;
  int d = (g >> 4) % DI;
  int bk = (g >> 4) / DI;
  float h = 0.f;
  for (int c = 0; c < NC; ++c) {
    size_t idx = (((size_t)bk * NC + c) * DI + d) * Nn + n;
    H0[idx] = h;
    h = P[idx] * h + Q[idx];
  }
}

// ---------------- scan pass C: replay + y emit (+ xs*Ds) ----------------
__global__ void scanC_kernel(const float* __restrict__ dtg, const float* __restrict__ xc,
                             const float* __restrict__ bsg, const float* __restrict__ csg,
                             const float* __restrict__ alog, const float* __restrict__ Dsv_,
                             const float* __restrict__ H0, float* __restrict__ outy) {
  int g = blockIdx.x * 256 + threadIdx.x;
  int n = g & 15;
  int t1 = g >> 4;
  int d = t1 % DI;
  int t2 = t1 / DI;
  int c = t2 & 63;
  int bk = t2 >> 6;
  int k = bk & 3, b = bk >> 2;
  float An = -__expf(alog[(k * DI + d) * Nn + n]);
  float Dsv = Dsv_[k * DI + d];
  const float* dtp = dtg + ((size_t)bk * DI + d) * Ll + c * 64;
  const float* bsp = bsg + ((size_t)bk * Ll + c * 64) * Nn + n;
  const float* csp = csg + ((size_t)bk * Ll + c * 64) * Nn + n;
  int p0, dp; dir_p0_dp(k, c, p0, dp);
  const float* up = xc + ((size_t)b * Ll + p0) * DI + d;
  int ustep = dp * DI;
  float* yo = outy + ((size_t)bk * Ll + c * 64) * DI + d;
  float h = H0[g];
  for (int t = 0; t < 64; ++t) {
    float dtv = dtp[t];
    float u = *up; up += ustep;
    float Bv = *bsp; bsp += Nn;
    float Cv = *csp; csp += Nn;
    float a = __expf(dtv * An);
    h = h * a + dtv * u * Bv;
    float yp = h * Cv;
    yp += __shfl_xor(yp, 8, 16);
    yp += __shfl_xor(yp, 4, 16);
    yp += __shfl_xor(yp, 2, 16);
    yp += __shfl_xor(yp, 1, 16);
    if (n == 0) yo[(size_t)t * DI] = yp + u * Dsv;
  }
}

// ---------------- combine 4 dirs + out_norm LN + silu(z) gate ----------------
__global__ void ycomb_kernel(const float* __restrict__ outy, const float* __restrict__ zs,
                             const float* __restrict__ g, const float* __restrict__ bt,
                             float* __restrict__ ygate) {
  int lane = threadIdx.x & 63;
  int pix = blockIdx.x * 4 + (threadIdx.x >> 6);
  int p = pix & 4095, b = pix >> 12;
  int l1 = ((p & 63) << 6) | (p >> 6);
  size_t base = (size_t)b * 4 * Ll * DI;
  const float* y0 = outy + base + (size_t)p * DI;
  const float* y2 = outy + base + ((size_t)2 * Ll + (4095 - p)) * DI;
  const float* y1 = outy + base + ((size_t)1 * Ll + l1) * DI;
  const float* y3 = outy + base + ((size_t)3 * Ll + (4095 - l1)) * DI;
  float v[3];
  #pragma unroll
  for (int j = 0; j < 3; ++j) {
    int d = lane + j * 64;
    v[j] = y0[d] + y2[d] + y1[d] + y3[d];
  }
  float s = wsum64(v[0] + v[1] + v[2]);
  float m = s * (1.f / 192.f);
  float q = wsum64(v[0] * v[0] + v[1] * v[1] + v[2] * v[2]);
  float rs = rsqrtf(q * (1.f / 192.f) - m * m + 1e-5f);
  const float* zrow = zs + (size_t)pix * DI;
  float* orow = ygate + (size_t)pix * DI;
  #pragma unroll
  for (int j = 0; j < 3; ++j) {
    int d = lane + j * 64;
    float yn = (v[j] - m) * rs * g[d] + bt[d];
    orow[d] = yn * zrow[d];
  }
}

// ---------------- residual + LN2 ----------------
__global__ void resln_kernel(const float* __restrict__ x4, const float* __restrict__ attn,
                             const float* __restrict__ fft, const float* __restrict__ ss,
                             const float* __restrict__ g, const float* __restrict__ bt,
                             float* __restrict__ xres, float* __restrict__ xn2) {
  int lane = threadIdx.x & 63;
  int pix = blockIdx.x * 4 + (threadIdx.x >> 6);
  size_t o = (size_t)pix * Cc;
  float v0 = x4[o + lane] * ss[lane] + attn[o + lane] + fft[o + lane];
  float v1 = 0.f;
  if (lane < 32) v1 = x4[o + lane + 64] * ss[lane + 64] + attn[o + lane + 64] + fft[o + lane + 64];
  float s = wsum64(v0 + v1);
  float m = s * (1.f / 96.f);
  float q = wsum64(v0 * v0 + v1 * v1);
  float rs = rsqrtf(q * (1.f / 96.f) - m * m + 1e-5f);
  xres[o + lane] = v0;
  xn2[o + lane] = (v0 - m) * rs * g[lane] + bt[lane];
  if (lane < 32) {
    xres[o + lane + 64] = v1;
    xn2[o + lane + 64] = (v1 - m) * rs * g[lane + 64] + bt[lane + 64];
  }
}

// ---------------- FFT branch: 64-point DFTs via twiddle table ----------------
__global__ void dft_row_kernel(const float* __restrict__ xf, float* __restrict__ Tr,
                               float* __restrict__ Ti) {
  __shared__ float row[64], cs[64], sn[64];
  int lane = threadIdx.x;
  int bch = blockIdx.x;  // (b*48+c)*64 + h
  row[lane] = xf[(size_t)bch * 64 + lane];
  float ang = (float)((double)lane * (2.0 * 3.14159265358979323846 / 64.0));
  float s0, c0; sincosf(ang, &s0, &c0); sn[lane] = s0; cs[lane] = c0;
  __syncthreads();
  if (lane < 33) {
    float ar = 0.f, ai = 0.f;
    for (int wq = 0; wq < 64; ++wq) {
      int j = (lane * wq) & 63;
      ar += row[wq] * cs[j];
      ai -= row[wq] * sn[j];
    }
    Tr[(size_t)bch * 33 + lane] = ar;
    Ti[(size_t)bch * 33 + lane] = ai;
  }
}

__global__ void dft_col_kernel(const float* __restrict__ Tr, const float* __restrict__ Ti,
                               float* __restrict__ Gr, float* __restrict__ Gi) {
  __shared__ float tr[64], ti[64], cs[64], sn[64];
  int lane = threadIdx.x;  // = u
  int v = blockIdx.x % 33, bc = blockIdx.x / 33;
  tr[lane] = Tr[((size_t)bc * 64 + lane) * 33 + v];
  ti[lane] = Ti[((size_t)bc * 64 + lane) * 33 + v];
  float ang = (float)((double)lane * (2.0 * 3.14159265358979323846 / 64.0));
  float s0, c0; sincosf(ang, &s0, &c0); sn[lane] = s0; cs[lane] = c0;
  __syncthreads();
  float ar = 0.f, ai = 0.f;
  for (int hh = 0; hh < 64; ++hh) {
    int j = (lane * hh) & 63;
    ar += tr[hh] * cs[j] + ti[hh] * sn[j];
    ai += ti[hh] * cs[j] - tr[hh] * sn[j];
  }
  Gr[((size_t)bc * 64 + lane) * 33 + v] = ar * (1.f / 64.f);
  Gi[((size_t)bc * 64 + lane) * 33 + v] = ai * (1.f / 64.f);
}

__global__ void fmix_kernel(const float* __restrict__ Gr, const float* __restrict__ Gi,
                            const float* __restrict__ w, const float* __restrict__ bias,
                            float* __restrict__ Mr, float* __restrict__ Mi) {
  __shared__ float fin[96];
  int tid = threadIdx.x;
  int b = blockIdx.x / 2112, uv = blockIdx.x % 2112;
  if (tid < 96) {
    size_t src = ((size_t)(b * 48 + (tid >> 1))) * 2112 + uv;
    fin[tid] = (tid & 1) ? Gi[src] : Gr[src];
  }
  __syncthreads();
  if (tid < 96) {
    float acc = bias[tid];
    const float* wr = w + tid * 96;
    #pragma unroll 8
    for (int ci = 0; ci < 96; ++ci) acc += fin[ci] * wr[ci];
    acc = silu_(acc);
    size_t dst = ((size_t)(b * 48 + (tid >> 1))) * 2112 + uv;
    if (tid & 1) Mi[dst] = acc; else Mr[dst] = acc;
  }
}

__global__ void idft_col_kernel(const float* __restrict__ Mr, const float* __restrict__ Mi,
                                float* __restrict__ gr, float* __restrict__ gi) {
  __shared__ float mr[64], mi[64], cs[64], sn[64];
  int lane = threadIdx.x;  // = h
  int v = blockIdx.x % 33, bc = blockIdx.x / 33;
  mr[lane] = Mr[((size_t)bc * 64 + lane) * 33 + v];
  mi[lane] = Mi[((size_t)bc * 64 + lane) * 33 + v];
  float ang = (float)((double)lane * (2.0 * 3.14159265358979323846 / 64.0));
  float s0, c0; sincosf(ang, &s0, &c0); sn[lane] = s0; cs[lane] = c0;
  __syncthreads();
  float ar = 0.f, ai = 0.f;
  for (int u = 0; u < 64; ++u) {
    int j = (lane * u) & 63;
    ar += mr[u] * cs[j] - mi[u] * sn[j];
    ai += mr[u] * sn[j] + mi[u] * cs[j];
  }
  gr[((size_t)bc * 64 + lane) * 33 + v] = ar;
  gi[((size_t)bc * 64 + lane) * 33 + v] = ai;
}

__global__ void irfft_row_kernel(const float* __restrict__ gr, const float* __restrict__ gi,
                                 float* __restrict__ ysp) {
  __shared__ float r[33], im[33], cs[64], sn[64];
  int lane = threadIdx.x;  // = w
  int bch = blockIdx.x;    // (b*48+c)*64 + h
  if (lane < 33) { r[lane] = gr[(size_t)bch * 33 + lane]; im[lane] = gi[(size_t)bch * 33 + lane]; }
  float ang = (float)((double)lane * (2.0 * 3.14159265358979323846 / 64.0));
  float s0, c0; sincosf(ang, &s0, &c0); sn[lane] = s0; cs[lane] = c0;
  __syncthreads();
  float acc = r[0] + ((lane & 1) ? -r[32] : r[32]);
  for (int v = 1; v < 32; ++v) {
    int j = (v * lane) & 63;
    acc += 2.f * (r[v] * cs[j] - im[v] * sn[j]);
  }
  ysp[(size_t)bch * 64 + lane] = acc * (1.f / 64.f);
}

// ---------------- MGCB depthwise + gelu gate ----------------
__global__ void mgcb_dw_kernel(const float* __restrict__ pm, const float* __restrict__ w3,
                               const float* __restrict__ w5, float* __restrict__ ymg) {
  int idx = blockIdx.x * 256 + threadIdx.x;  // (b*L+p)*192 + cc
  int cc = idx % DI;
  int p = (idx / DI) & (Ll - 1);
  int b = idx / (DI * Ll);
  int h = p >> 6, wq = p & 63;
  const float* base = pm + (size_t)b * Ll * 384;
  const float* wr = w3 + cc * 9;
  float gg = 0.f;
  #pragma unroll
  for (int i = 0; i < 3; ++i) {
    int hh = h - 1 + i; if ((unsigned)hh >= 64u) continue;
    #pragma unroll
    for (int j = 0; j < 3; ++j) {
      int ww2 = wq - 1 + j; if ((unsigned)ww2 >= 64u) continue;
      gg += base[(size_t)(hh * 64 + ww2) * 384 + cc] * wr[i * 3 + j];
    }
  }
  float mm = 0.f;
  if (cc < 96) {
    int c2 = 192 + cc;
    const float* wr2 = w3 + c2 * 9;
    #pragma unroll
    for (int i = 0; i < 3; ++i) {
      int hh = h - 1 + i; if ((unsigned)hh >= 64u) continue;
      #pragma unroll
      for (int j = 0; j < 3; ++j) {
        int ww2 = wq - 1 + j; if ((unsigned)ww2 >= 64u) continue;
        mm += base[(size_t)(hh * 64 + ww2) * 384 + c2] * wr2[i * 3 + j];
      }
    }
  } else {
    int c5 = 288 + (cc - 96);
    const float* wr5 = w5 + (cc - 96) * 25;
    #pragma unroll
    for (int i = 0; i < 5; ++i) {
      int hh = h - 2 + i; if ((unsigned)hh >= 64u) continue;
      #pragma unroll
      for (int j = 0; j < 5; ++j) {
        int ww2 = wq - 2 + j; if ((unsigned)ww2 >= 64u) continue;
        mm += base[(size_t)(hh * 64 + ww2) * 384 + c5] * wr5[i * 5 + j];
      }
    }
  }
  float ge = 0.5f * gg * (1.f + erff(gg * 0.70710678118654752f));
  ymg[idx] = ge * mm;
}

// ---------------- channel attention ----------------
__global__ void camean_kernel(const float* __restrict__ yc, float* __restrict__ means) {
  __shared__ float red[256];
  int c = blockIdx.x % 96, b = blockIdx.x / 96;
  float s = 0.f;
  for (int p = threadIdx.x; p < Ll; p += 256) s += yc[((size_t)b * Ll + p) * Cc + c];
  red[threadIdx.x] = s; __syncthreads();
  for (int st = 128; st > 0; st >>= 1) {
    if (threadIdx.x < st) red[threadIdx.x] += red[threadIdx.x + st];
    __syncthreads();
  }
  if (threadIdx.x == 0) means[b * 96 + c] = red[0] * (1.f / 4096.f);
}

__global__ void camlp_kernel(const float* __restrict__ means, const float* __restrict__ w1,
                             const float* __restrict__ b1, const float* __restrict__ w2,
                             const float* __restrict__ b2, float* __restrict__ avec) {
  int c = threadIdx.x;
  if (c >= 96) return;
  for (int b = 0; b < 2; ++b) {
    float t[3];
    #pragma unroll
    for (int j = 0; j < 3; ++j) {
      float a = b1[j];
      for (int cc = 0; cc < 96; ++cc) a += means[b * 96 + cc] * w1[j * 96 + cc];
      t[j] = fmaxf(a, 0.f);
    }
    float a2 = b2[c];
    #pragma unroll
    for (int j = 0; j < 3; ++j) a2 += t[j] * w2[c * 3 + j];
    avec[b * 96 + c] = 1.f / (1.f + expf(-a2));
  }
}

__global__ void final_kernel(const float* __restrict__ xres, const float* __restrict__ yc,
                             const float* __restrict__ ss2, const float* __restrict__ avec,
                             float* __restrict__ out) {
  int idx = blockIdx.x * 256 + threadIdx.x;  // 786432
  int c = idx % 96;
  int b = idx / (Ll * 96);
  out[idx] = xres[idx] * ss2[c] + yc[idx] * avec[b * 96 + c];
}

// ---------------- host ----------------
extern "C" void kernel_launch(void* const* d_in, const int* in_sizes, int n_in,
                              void* d_out, int out_size, void* d_ws, size_t ws_size,
                              hipStream_t stream) {
  const float* input      = (const float*)d_in[0];
  const float* ln1_g      = (const float*)d_in[1];
  const float* ln1_b      = (const float*)d_in[2];
  const float* skip_scale = (const float*)d_in[3];
  const float* skip_scale2= (const float*)d_in[4];
  const float* ln2_g      = (const float*)d_in[5];
  const float* ln2_b      = (const float*)d_in[6];
  const float* in_proj_w  = (const float*)d_in[7];
  const float* conv2d_w   = (const float*)d_in[8];
  const float* conv2d_b   = (const float*)d_in[9];
  const float* x_proj_w   = (const float*)d_in[10];
  const float* dt_proj_w  = (const float*)d_in[11];
  const float* dt_proj_b  = (const float*)d_in[12];
  const float* A_logs     = (const float*)d_in[13];
  const float* Ds         = (const float*)d_in[14];
  const float* out_norm_g = (const float*)d_in[15];
  const float* out_norm_b = (const float*)d_in[16];
  const float* out_proj_w = (const float*)d_in[17];
  const float* f1_w       = (const float*)d_in[18];
  const float* f1_b       = (const float*)d_in[19];
  const float* fm_w       = (const float*)d_in[20];
  const float* fm_b       = (const float*)d_in[21];
  const float* f2_w       = (const float*)d_in[22];
  const float* f2_b       = (const float*)d_in[23];
  const float* mg_in_w    = (const float*)d_in[24];
  const float* mg_dw3_w   = (const float*)d_in[25];
  const float* mg_dw5_w   = (const float*)d_in[26];
  const float* mg_out_w   = (const float*)d_in[27];
  const float* ca_w1      = (const float*)d_in[28];
  const float* ca_b1      = (const float*)d_in[29];
  const float* ca_w2      = (const float*)d_in[30];
  const float* ca_b2      = (const float*)d_in[31];

  float* W = (float*)d_ws;   // needs ~115 MB
  float* XN    = W;                     // 786432
  float* ZSILU = XN + 786432;           // 1572864
  float* XX    = ZSILU + 1572864;       // 1572864
  float* XC    = XX + 1572864;          // 1572864
  float* DT    = XC + 1572864;          // 6291456
  float* BSb   = DT + 6291456;          // 524288
  float* CSb   = BSb + 524288;          // 524288
  float* PP    = CSb + 524288;          // 1572864
  float* QQ    = PP + 1572864;          // 1572864
  float* H0    = QQ + 1572864;          // 1572864
  float* OUTY  = H0 + 1572864;          // 6291456
  float* YGATE = OUTY + 6291456;        // 1572864
  float* ATTN  = YGATE + 1572864;       // 786432
  float* FFTOUT= ATTN + 786432;         // 786432
  float* XRES  = FFTOUT + 786432;       // 786432
  float* XN2   = XRES + 786432;         // 786432
  float* MEANS = XN2 + 786432;          // 192
  float* AVEC  = MEANS + 192;           // 192
  // FFT scratch overlays PP/QQ (dead after scanB; FFT chain runs after scanB)
  float* XF  = PP;                      // 393216
  float* TR  = XF + 393216;             // 202752
  float* TI  = TR + 202752;
  float* GR  = TI + 202752;
  float* GI  = GR + 202752;
  float* MR  = TR;                      // reuse (TR/TI dead after dft_col)
  float* MI  = TI;
  float* G2R = GR;                      // reuse (GR/GI dead after fmix)
  float* G2I = GI;
  float* YSP = GI + 202752;             // 393216
  // MGCB overlays DT region (dead after scanC)
  float* PMG = DT;                      // 3145728
  float* YMG = DT + 3145728;            // 1572864
  float* YCb = YMG + 1572864;           // 786432

  // 1) LN1
  ln1_kernel<<<2048, 256, 0, stream>>>(input, ln1_g, ln1_b, XN);
  // 2) in_proj -> xx, silu(z)
  conv1x1_kernel<96, 384, 0, 2, 0, 0><<<512, 256, 0, stream>>>(XN, in_proj_w, nullptr, XX, ZSILU);
  // 3) dwconv3x3 + bias + silu
  dwconv3_silu_kernel<<<6144, 256, 0, stream>>>(XX, conv2d_w, conv2d_b, XC);
  // 4) x_proj/dt_proj/softplus
  proj_kernel<<<512, 256, 0, stream>>>(XC, x_proj_w, dt_proj_w, dt_proj_b, BSb, CSb, DT);
  // 5-6) scan passes A, B
  scanA_kernel<<<6144, 256, 0, stream>>>(DT, XC, BSb, A_logs, PP, QQ);
  scanB_kernel<<<96, 256, 0, stream>>>(PP, QQ, H0);
  // FFT branch (after scanB so it may overlay PP/QQ)
  conv1x1_kernel<96, 48, 0, 1, 1, 1><<<512, 256, 0, stream>>>(XN, f1_w, f1_b, XF, nullptr);
  dft_row_kernel<<<6144, 64, 0, stream>>>(XF, TR, TI);
  dft_col_kernel<<<3168, 64, 0, stream>>>(TR, TI, GR, GI);
  fmix_kernel<<<4224, 128, 0, stream>>>(GR, GI, fm_w, fm_b, MR, MI);
  idft_col_kernel<<<3168, 64, 0, stream>>>(MR, MI, G2R, G2I);
  irfft_row_kernel<<<6144, 64, 0, stream>>>(G2R, G2I, YSP);
  conv1x1_kernel<48, 96, 1, 0, 0, 1><<<512, 256, 0, stream>>>(YSP, f2_w, f2_b, FFTOUT, nullptr);
  // 7) scan pass C
  scanC_kernel<<<6144, 256, 0, stream>>>(DT, XC, BSb, CSb, A_logs, Ds, H0, OUTY);
  // 8) combine dirs + out_norm + gate
  ycomb_kernel<<<2048, 256, 0, stream>>>(OUTY, ZSILU, out_norm_g, out_norm_b, YGATE);
  // 9) out_proj
  conv1x1_kernel<192, 96, 0, 0, 0, 0><<<512, 256, 0, stream>>>(YGATE, out_proj_w, nullptr, ATTN, nullptr);
  // 10) residual + LN2
  resln_kernel<<<2048, 256, 0, stream>>>(input, ATTN, FFTOUT, skip_scale, ln2_g, ln2_b, XRES, XN2);
  // MGCB
  conv1x1_kernel<96, 384, 0, 0, 0, 0><<<512, 256, 0, stream>>>(XN2, mg_in_w, nullptr, PMG, nullptr);
  mgcb_dw_kernel<<<6144, 256, 0, stream>>>(PMG, mg_dw3_w, mg_dw5_w, YMG);
  conv1x1_kernel<192, 96, 0, 0, 0, 0><<<512, 256, 0, stream>>>(YMG, mg_out_w, nullptr, YCb, nullptr);
  camean_kernel<<<192, 256, 0, stream>>>(YCb, MEANS);
  camlp_kernel<<<1, 128, 0, stream>>>(MEANS, ca_w1, ca_b1, ca_w2, ca_b2, AVEC);
  final_kernel<<<3072, 256, 0, stream>>>(XRES, YCb, skip_scale2, AVEC, (float*)d_out);
}

// Round 2
// 502.129 us; speedup vs baseline: 1.1120x; 1.1120x over previous
//
#include <hip/hip_runtime.h>
#include <math.h>

#define DEV __device__ __forceinline__

constexpr int DI = 192, Nn = 16, Rr = 6;
constexpr int Cc = 96;
constexpr int Ll = 4096;           // 64*64
constexpr int NC = 64;             // scan chunks of 64 steps

DEV float silu_(float x) { return x / (1.f + __expf(-x)); }
DEV float wsum64(float v) {
  #pragma unroll
  for (int m = 32; m; m >>= 1) v += __shfl_xor(v, m, 64);
  return v;
}
// quad (4-lane) butterfly adds via DPP quad_perm — VALU pipe, no LDS
DEV float qadd1(float v) {
  int i = __builtin_amdgcn_mov_dpp(__float_as_int(v), 0xB1, 0xF, 0xF, true); // [1,0,3,2]
  return v + __int_as_float(i);
}
DEV float qadd2(float v) {
  int i = __builtin_amdgcn_mov_dpp(__float_as_int(v), 0x4E, 0xF, 0xF, true); // [2,3,0,1]
  return v + __int_as_float(i);
}

// ---------------- LN over C=96 (wave per pixel) ----------------
__global__ void ln1_kernel(const float* __restrict__ x, const float* __restrict__ g,
                           const float* __restrict__ bt, float* __restrict__ xn) {
  int lane = threadIdx.x & 63;
  int pix = blockIdx.x * 4 + (threadIdx.x >> 6);
  const float* row = x + (size_t)pix * Cc;
  float v0 = row[lane];
  float v1 = (lane < 32) ? row[lane + 64] : 0.f;
  float s = wsum64(v0 + v1);
  float m = s * (1.f / 96.f);
  float q = wsum64(v0 * v0 + v1 * v1);
  float rs = rsqrtf(q * (1.f / 96.f) - m * m + 1e-6f);
  float* o = xn + (size_t)pix * Cc;
  o[lane] = (v0 - m) * rs * g[lane] + bt[lane];
  if (lane < 32) o[lane + 64] = (v1 - m) * rs * g[lane + 64] + bt[lane + 64];
}

// ---------------- generic 1x1 conv (GEMM over channels) ----------------
template<int CIN, int COUT, int IN_MODE, int OUT_MODE, int ACT, int HAS_BIAS>
__global__ void conv1x1_kernel(const float* __restrict__ in, const float* __restrict__ w,
                               const float* __restrict__ bias, float* __restrict__ out,
                               float* __restrict__ out2) {
  __shared__ float s_in[16][CIN + 1];
  int tid = threadIdx.x;
  int pbase = blockIdx.x * 16;
  for (int idx = tid; idx < 16 * CIN; idx += 256) {
    int px = idx / CIN, cc = idx - px * CIN;
    int gp = pbase + px;
    float v;
    if (IN_MODE == 0) v = in[(size_t)gp * CIN + cc];
    else { int b = gp >> 12, p = gp & 4095; v = in[((size_t)b * CIN + cc) * Ll + p]; }
    s_in[px][cc] = v;
  }
  __syncthreads();
  int px = tid & 15, og = tid >> 4;
  int gp = pbase + px;
  for (int oc = og; oc < COUT; oc += 16) {
    float acc = HAS_BIAS ? bias[oc] : 0.f;
    const float* wr = w + (size_t)oc * CIN;
    #pragma unroll 8
    for (int c = 0; c < CIN; ++c) acc += s_in[px][c] * wr[c];
    if (OUT_MODE == 2) {
      if (oc < 192) out[(size_t)gp * 192 + oc] = acc;
      else out2[(size_t)gp * 192 + (oc - 192)] = silu_(acc);
    } else {
      if (ACT == 1) acc = silu_(acc);
      if (OUT_MODE == 0) out[(size_t)gp * COUT + oc] = acc;
      else { int b = gp >> 12, p = gp & 4095; out[((size_t)b * COUT + oc) * Ll + p] = acc; }
    }
  }
}

// ---------------- depthwise 3x3 + bias + silu (NHWC, 192 ch) ----------------
__global__ void dwconv3_silu_kernel(const float* __restrict__ xx, const float* __restrict__ w,
                                    const float* __restrict__ bias, float* __restrict__ xc) {
  int idx = blockIdx.x * 256 + threadIdx.x;   // (b*L+p)*DI + d
  int d = idx % DI;
  int p = (idx / DI) & (Ll - 1);
  int b = idx / (DI * Ll);
  int h = p >> 6, wq = p & 63;
  const float* base = xx + (size_t)b * Ll * DI + d;
  const float* wr = w + d * 9;
  float acc = bias[d];
  #pragma unroll
  for (int i = 0; i < 3; ++i) {
    int hh = h - 1 + i;
    if ((unsigned)hh >= 64u) continue;
    #pragma unroll
    for (int j = 0; j < 3; ++j) {
      int ww2 = wq - 1 + j;
      if ((unsigned)ww2 >= 64u) continue;
      acc += base[(size_t)(hh * 64 + ww2) * DI] * wr[i * 3 + j];
    }
  }
  xc[idx] = silu_(acc);
}

// ---------------- x_proj + dt_proj + softplus (per (b,k,l)) ----------------
__global__ void proj_kernel(const float* __restrict__ xc, const float* __restrict__ xpw,
                            const float* __restrict__ dtw, const float* __restrict__ dtb,
                            float* __restrict__ BSo, float* __restrict__ CSo,
                            float* __restrict__ DTo) {
  __shared__ float xv[64][193];
  __shared__ float dts[64][9];
  int tid = threadIdx.x;
  int lane = tid & 63, wv = tid >> 6;
  int lb = (blockIdx.x & 63) * 64;
  int k = (blockIdx.x >> 6) & 3;
  int b = blockIdx.x >> 8;
  int bk = b * 4 + k;
  for (int it = wv; it < 64; it += 4) {
    int l = lb + it;
    int p;
    if (k == 0) p = l;
    else if (k == 1) p = ((l & 63) << 6) | (l >> 6);
    else if (k == 2) p = 4095 - l;
    else { int lr = 4095 - l; p = ((lr & 63) << 6) | (lr >> 6); }
    const float* src = xc + ((size_t)b * Ll + p) * DI;
    xv[it][lane]       = src[lane];
    xv[it][lane + 64]  = src[lane + 64];
    xv[it][lane + 128] = src[lane + 128];
  }
  __syncthreads();
  int i = lane, cg = wv;
  int l = lb + i;
  for (int c = cg; c < 38; c += 4) {
    const float* wr = xpw + ((size_t)k * 38 + c) * DI;
    float acc = 0.f;
    #pragma unroll 8
    for (int j = 0; j < DI; ++j) acc += xv[i][j] * wr[j];
    if (c < 6) dts[i][c] = acc;
    else if (c < 22) BSo[((size_t)bk * Ll + l) * Nn + (c - 6)] = acc;
    else             CSo[((size_t)bk * Ll + l) * Nn + (c - 22)] = acc;
  }
  __syncthreads();
  for (int d = cg; d < DI; d += 4) {
    float acc = dtb[k * DI + d];
    const float* wr = dtw + ((size_t)k * DI + d) * Rr;
    #pragma unroll
    for (int r = 0; r < Rr; ++r) acc += dts[i][r] * wr[r];
    float sp = (acc > 20.f) ? acc : log1pf(__expf(acc));
    DTo[((size_t)bk * DI + d) * Ll + l] = sp;
  }
}

// ---------------- scan helpers: direction start/stride within chunk ----------------
DEV void dir_p0_dp(int k, int c, int& p0, int& dp) {
  if (k == 0) { p0 = c * 64; dp = 1; }
  else if (k == 1) { p0 = c; dp = 64; }
  else if (k == 2) { p0 = 4095 - c * 64; dp = -1; }
  else { p0 = 4095 - c; dp = -64; }
}

// ---------------- scan pass A: per-chunk (prod a, partial), 4 n-states/thread ----------------
__global__ void scanA_kernel(const float* __restrict__ dtg, const float* __restrict__ xc,
                             const float* __restrict__ bsg, const float* __restrict__ alog,
                             float* __restrict__ P, float* __restrict__ Q) {
  int g = blockIdx.x * 256 + threadIdx.x;   // ((bk*64+c)*192+d)*4+ng
  int ng = g & 3;
  int t1 = g >> 2;
  int d = t1 % DI;
  int t2 = t1 / DI;
  int c = t2 & 63;
  int bk = t2 >> 6;
  int k = bk & 3, b = bk >> 2;
  float4 al = ((const float4*)alog)[(size_t)(k * DI + d) * 4 + ng];
  float An0 = -__expf(al.x), An1 = -__expf(al.y), An2 = -__expf(al.z), An3 = -__expf(al.w);
  const float* dtp = dtg + ((size_t)bk * DI + d) * Ll + c * 64;
  const float4* bsp = (const float4*)bsg + ((size_t)bk * Ll + c * 64) * 4 + ng;
  int p0, dp; dir_p0_dp(k, c, p0, dp);
  const float* up = xc + ((size_t)b * Ll + p0) * DI + d;
  int ustep = dp * DI;
  float P0 = 1.f, P1 = 1.f, P2 = 1.f, P3 = 1.f;
  float Q0 = 0.f, Q1 = 0.f, Q2 = 0.f, Q3 = 0.f;
  #pragma unroll 4
  for (int t = 0; t < 64; ++t) {
    float dtv = dtp[t];
    float u = *up; up += ustep;
    float4 Bv = *bsp; bsp += 4;
    float s = dtv * u;
    float a0 = __expf(dtv * An0), a1 = __expf(dtv * An1);
    float a2 = __expf(dtv * An2), a3 = __expf(dtv * An3);
    P0 *= a0; P1 *= a1; P2 *= a2; P3 *= a3;
    Q0 = Q0 * a0 + s * Bv.x; Q1 = Q1 * a1 + s * Bv.y;
    Q2 = Q2 * a2 + s * Bv.z; Q3 = Q3 * a3 + s * Bv.w;
  }
  ((float4*)P)[g] = make_float4(P0, P1, P2, P3);
  ((float4*)Q)[g] = make_float4(Q0, Q1, Q2, Q3);
}

// ---------------- scan pass B: cross-chunk prefix ----------------
__global__ void scanB_kernel(const float* __restrict__ P, const float* __restrict__ Q,
                             float* __restrict__ H0) {
  int g = blockIdx.x * 256 + threadIdx.x;   // (bk*192+d)*16+n, 24576
  int n = g & 15;
  int d = (g >> 4) % DI;
  int bk = (g >> 4) / DI;
  float h = 0.f;
  for (int c = 0; c < NC; ++c) {
    size_t idx = (((size_t)bk * NC + c) * DI + d) * Nn + n;
    H0[idx] = h;
    h = P[idx] * h + Q[idx];
  }
}

// ---------------- scan pass C: replay + y emit (+ xs*Ds), 4 n-states/thread ----------------
__global__ void scanC_kernel(const float* __restrict__ dtg, const float* __restrict__ xc,
                             const float* __restrict__ bsg, const float* __restrict__ csg,
                             const float* __restrict__ alog, const float* __restrict__ Dsv_,
                             const float* __restrict__ H0, float* __restrict__ outy) {
  int g = blockIdx.x * 256 + threadIdx.x;
  int ng = g & 3;
  int t1 = g >> 2;
  int d = t1 % DI;
  int t2 = t1 / DI;
  int c = t2 & 63;
  int bk = t2 >> 6;
  int k = bk & 3, b = bk >> 2;
  float4 al = ((const float4*)alog)[(size_t)(k * DI + d) * 4 + ng];
  float An0 = -__expf(al.x), An1 = -__expf(al.y), An2 = -__expf(al.z), An3 = -__expf(al.w);
  float Dsv = Dsv_[k * DI + d];
  const float* dtp = dtg + ((size_t)bk * DI + d) * Ll + c * 64;
  const float4* bsp = (const float4*)bsg + ((size_t)bk * Ll + c * 64) * 4 + ng;
  const float4* csp = (const float4*)csg + ((size_t)bk * Ll + c * 64) * 4 + ng;
  int p0, dp; dir_p0_dp(k, c, p0, dp);
  const float* up = xc + ((size_t)b * Ll + p0) * DI + d;
  int ustep = dp * DI;
  float* yo = outy + ((size_t)bk * Ll + c * 64) * DI + d;
  float4 h4 = ((const float4*)H0)[g];
  float h0 = h4.x, h1 = h4.y, h2 = h4.z, h3 = h4.w;
  #pragma unroll 4
  for (int t = 0; t < 64; ++t) {
    float dtv = dtp[t];
    float u = *up; up += ustep;
    float4 Bv = *bsp; bsp += 4;
    float4 Cv = *csp; csp += 4;
    float s = dtv * u;
    float a0 = __expf(dtv * An0), a1 = __expf(dtv * An1);
    float a2 = __expf(dtv * An2), a3 = __expf(dtv * An3);
    h0 = h0 * a0 + s * Bv.x; h1 = h1 * a1 + s * Bv.y;
    h2 = h2 * a2 + s * Bv.z; h3 = h3 * a3 + s * Bv.w;
    float yp = h0 * Cv.x + h1 * Cv.y + h2 * Cv.z + h3 * Cv.w;
    yp = qadd1(yp);
    yp = qadd2(yp);
    if (ng == 0) yo[(size_t)t * DI] = yp + u * Dsv;
  }
}

// ---------------- combine 4 dirs + out_norm LN + silu(z) gate ----------------
__global__ void ycomb_kernel(const float* __restrict__ outy, const float* __restrict__ zs,
                             const float* __restrict__ g, const float* __restrict__ bt,
                             float* __restrict__ ygate) {
  int lane = threadIdx.x & 63;
  int pix = blockIdx.x * 4 + (threadIdx.x >> 6);
  int p = pix & 4095, b = pix >> 12;
  int l1 = ((p & 63) << 6) | (p >> 6);
  size_t base = (size_t)b * 4 * Ll * DI;
  const float* y0 = outy + base + (size_t)p * DI;
  const float* y2 = outy + base + ((size_t)2 * Ll + (4095 - p)) * DI;
  const float* y1 = outy + base + ((size_t)1 * Ll + l1) * DI;
  const float* y3 = outy + base + ((size_t)3 * Ll + (4095 - l1)) * DI;
  float v[3];
  #pragma unroll
  for (int j = 0; j < 3; ++j) {
    int d = lane + j * 64;
    v[j] = y0[d] + y2[d] + y1[d] + y3[d];
  }
  float s = wsum64(v[0] + v[1] + v[2]);
  float m = s * (1.f / 192.f);
  float q = wsum64(v[0] * v[0] + v[1] * v[1] + v[2] * v[2]);
  float rs = rsqrtf(q * (1.f / 192.f) - m * m + 1e-5f);
  const float* zrow = zs + (size_t)pix * DI;
  float* orow = ygate + (size_t)pix * DI;
  #pragma unroll
  for (int j = 0; j < 3; ++j) {
    int d = lane + j * 64;
    float yn = (v[j] - m) * rs * g[d] + bt[d];
    orow[d] = yn * zrow[d];
  }
}

// ---------------- residual + LN2 ----------------
__global__ void resln_kernel(const float* __restrict__ x4, const float* __restrict__ attn,
                             const float* __restrict__ fft, const float* __restrict__ ss,
                             const float* __restrict__ g, const float* __restrict__ bt,
                             float* __restrict__ xres, float* __restrict__ xn2) {
  int lane = threadIdx.x & 63;
  int pix = blockIdx.x * 4 + (threadIdx.x >> 6);
  size_t o = (size_t)pix * Cc;
  float v0 = x4[o + lane] * ss[lane] + attn[o + lane] + fft[o + lane];
  float v1 = 0.f;
  if (lane < 32) v1 = x4[o + lane + 64] * ss[lane + 64] + attn[o + lane + 64] + fft[o + lane + 64];
  float s = wsum64(v0 + v1);
  float m = s * (1.f / 96.f);
  float q = wsum64(v0 * v0 + v1 * v1);
  float rs = rsqrtf(q * (1.f / 96.f) - m * m + 1e-5f);
  xres[o + lane] = v0;
  xn2[o + lane] = (v0 - m) * rs * g[lane] + bt[lane];
  if (lane < 32) {
    xres[o + lane + 64] = v1;
    xn2[o + lane + 64] = (v1 - m) * rs * g[lane + 64] + bt[lane + 64];
  }
}

// ---------------- FFT branch: 64-point DFTs via twiddle table ----------------
__global__ void dft_row_kernel(const float* __restrict__ xf, float* __restrict__ Tr,
                               float* __restrict__ Ti) {
  __shared__ float row[64], cs[64], sn[64];
  int lane = threadIdx.x;
  int bch = blockIdx.x;  // (b*48+c)*64 + h
  row[lane] = xf[(size_t)bch * 64 + lane];
  float ang = (float)((double)lane * (2.0 * 3.14159265358979323846 / 64.0));
  float s0, c0; sincosf(ang, &s0, &c0); sn[lane] = s0; cs[lane] = c0;
  __syncthreads();
  if (lane < 33) {
    float ar = 0.f, ai = 0.f;
    for (int wq = 0; wq < 64; ++wq) {
      int j = (lane * wq) & 63;
      ar += row[wq] * cs[j];
      ai -= row[wq] * sn[j];
    }
    Tr[(size_t)bch * 33 + lane] = ar;
    Ti[(size_t)bch * 33 + lane] = ai;
  }
}

__global__ void dft_col_kernel(const float* __restrict__ Tr, const float* __restrict__ Ti,
                               float* __restrict__ Gr, float* __restrict__ Gi) {
  __shared__ float tr[64], ti[64], cs[64], sn[64];
  int lane = threadIdx.x;  // = u
  int v = blockIdx.x % 33, bc = blockIdx.x / 33;
  tr[lane] = Tr[((size_t)bc * 64 + lane) * 33 + v];
  ti[lane] = Ti[((size_t)bc * 64 + lane) * 33 + v];
  float ang = (float)((double)lane * (2.0 * 3.14159265358979323846 / 64.0));
  float s0, c0; sincosf(ang, &s0, &c0); sn[lane] = s0; cs[lane] = c0;
  __syncthreads();
  float ar = 0.f, ai = 0.f;
  for (int hh = 0; hh < 64; ++hh) {
    int j = (lane * hh) & 63;
    ar += tr[hh] * cs[j] + ti[hh] * sn[j];
    ai += ti[hh] * cs[j] - tr[hh] * sn[j];
  }
  Gr[((size_t)bc * 64 + lane) * 33 + v] = ar * (1.f / 64.f);
  Gi[((size_t)bc * 64 + lane) * 33 + v] = ai * (1.f / 64.f);
}

__global__ void fmix_kernel(const float* __restrict__ Gr, const float* __restrict__ Gi,
                            const float* __restrict__ w, const float* __restrict__ bias,
                            float* __restrict__ Mr, float* __restrict__ Mi) {
  __shared__ float fin[96];
  int tid = threadIdx.x;
  int b = blockIdx.x / 2112, uv = blockIdx.x % 2112;
  if (tid < 96) {
    size_t src = ((size_t)(b * 48 + (tid >> 1))) * 2112 + uv;
    fin[tid] = (tid & 1) ? Gi[src] : Gr[src];
  }
  __syncthreads();
  if (tid < 96) {
    float acc = bias[tid];
    const float* wr = w + tid * 96;
    #pragma unroll 8
    for (int ci = 0; ci < 96; ++ci) acc += fin[ci] * wr[ci];
    acc = silu_(acc);
    size_t dst = ((size_t)(b * 48 + (tid >> 1))) * 2112 + uv;
    if (tid & 1) Mi[dst] = acc; else Mr[dst] = acc;
  }
}

__global__ void idft_col_kernel(const float* __restrict__ Mr, const float* __restrict__ Mi,
                                float* __restrict__ gr, float* __restrict__ gi) {
  __shared__ float mr[64], mi[64], cs[64], sn[64];
  int lane = threadIdx.x;  // = h
  int v = blockIdx.x % 33, bc = blockIdx.x / 33;
  mr[lane] = Mr[((size_t)bc * 64 + lane) * 33 + v];
  mi[lane] = Mi[((size_t)bc * 64 + lane) * 33 + v];
  float ang = (float)((double)lane * (2.0 * 3.14159265358979323846 / 64.0));
  float s0, c0; sincosf(ang, &s0, &c0); sn[lane] = s0; cs[lane] = c0;
  __syncthreads();
  float ar = 0.f, ai = 0.f;
  for (int u = 0; u < 64; ++u) {
    int j = (lane * u) & 63;
    ar += mr[u] * cs[j] - mi[u] * sn[j];
    ai += mr[u] * sn[j] + mi[u] * cs[j];
  }
  gr[((size_t)bc * 64 + lane) * 33 + v] = ar;
  gi[((size_t)bc * 64 + lane) * 33 + v] = ai;
}

__global__ void irfft_row_kernel(const float* __restrict__ gr, const float* __restrict__ gi,
                                 float* __restrict__ ysp) {
  __shared__ float r[33], im[33], cs[64], sn[64];
  int lane = threadIdx.x;  // = w
  int bch = blockIdx.x;    // (b*48+c)*64 + h
  if (lane < 33) { r[lane] = gr[(size_t)bch * 33 + lane]; im[lane] = gi[(size_t)bch * 33 + lane]; }
  float ang = (float)((double)lane * (2.0 * 3.14159265358979323846 / 64.0));
  float s0, c0; sincosf(ang, &s0, &c0); sn[lane] = s0; cs[lane] = c0;
  __syncthreads();
  float acc = r[0] + ((lane & 1) ? -r[32] : r[32]);
  for (int v = 1; v < 32; ++v) {
    int j = (v * lane) & 63;
    acc += 2.f * (r[v] * cs[j] - im[v] * sn[j]);
  }
  ysp[(size_t)bch * 64 + lane] = acc * (1.f / 64.f);
}

// ---------------- MGCB depthwise + gelu gate ----------------
__global__ void mgcb_dw_kernel(const float* __restrict__ pm, const float* __restrict__ w3,
                               const float* __restrict__ w5, float* __restrict__ ymg) {
  int idx = blockIdx.x * 256 + threadIdx.x;  // (b*L+p)*192 + cc
  int cc = idx % DI;
  int p = (idx / DI) & (Ll - 1);
  int b = idx / (DI * Ll);
  int h = p >> 6, wq = p & 63;
  const float* base = pm + (size_t)b * Ll * 384;
  const float* wr = w3 + cc * 9;
  float gg = 0.f;
  #pragma unroll
  for (int i = 0; i < 3; ++i) {
    int hh = h - 1 + i; if ((unsigned)hh >= 64u) continue;
    #pragma unroll
    for (int j = 0; j < 3; ++j) {
      int ww2 = wq - 1 + j; if ((unsigned)ww2 >= 64u) continue;
      gg += base[(size_t)(hh * 64 + ww2) * 384 + cc] * wr[i * 3 + j];
    }
  }
  float mm = 0.f;
  if (cc < 96) {
    int c2 = 192 + cc;
    const float* wr2 = w3 + c2 * 9;
    #pragma unroll
    for (int i = 0; i < 3; ++i) {
      int hh = h - 1 + i; if ((unsigned)hh >= 64u) continue;
      #pragma unroll
      for (int j = 0; j < 3; ++j) {
        int ww2 = wq - 1 + j; if ((unsigned)ww2 >= 64u) continue;
        mm += base[(size_t)(hh * 64 + ww2) * 384 + c2] * wr2[i * 3 + j];
      }
    }
  } else {
    int c5 = 288 + (cc - 96);
    const float* wr5 = w5 + (cc - 96) * 25;
    #pragma unroll
    for (int i = 0; i < 5; ++i) {
      int hh = h - 2 + i; if ((unsigned)hh >= 64u) continue;
      #pragma unroll
      for (int j = 0; j < 5; ++j) {
        int ww2 = wq - 2 + j; if ((unsigned)ww2 >= 64u) continue;
        mm += base[(size_t)(hh * 64 + ww2) * 384 + c5] * wr5[i * 5 + j];
      }
    }
  }
  float ge = 0.5f * gg * (1.f + erff(gg * 0.70710678118654752f));
  ymg[idx] = ge * mm;
}

// ---------------- channel attention ----------------
__global__ void camean_kernel(const float* __restrict__ yc, float* __restrict__ means) {
  __shared__ float red[256];
  int c = blockIdx.x % 96, b = blockIdx.x / 96;
  float s = 0.f;
  for (int p = threadIdx.x; p < Ll; p += 256) s += yc[((size_t)b * Ll + p) * Cc + c];
  red[threadIdx.x] = s; __syncthreads();
  for (int st = 128; st > 0; st >>= 1) {
    if (threadIdx.x < st) red[threadIdx.x] += red[threadIdx.x + st];
    __syncthreads();
  }
  if (threadIdx.x == 0) means[b * 96 + c] = red[0] * (1.f / 4096.f);
}

__global__ void camlp_kernel(const float* __restrict__ means, const float* __restrict__ w1,
                             const float* __restrict__ b1, const float* __restrict__ w2,
                             const float* __restrict__ b2, float* __restrict__ avec) {
  int c = threadIdx.x;
  if (c >= 96) return;
  for (int b = 0; b < 2; ++b) {
    float t[3];
    #pragma unroll
    for (int j = 0; j < 3; ++j) {
      float a = b1[j];
      for (int cc = 0; cc < 96; ++cc) a += means[b * 96 + cc] * w1[j * 96 + cc];
      t[j] = fmaxf(a, 0.f);
    }
    float a2 = b2[c];
    #pragma unroll
    for (int j = 0; j < 3; ++j) a2 += t[j] * w2[c * 3 + j];
    avec[b * 96 + c] = 1.f / (1.f + expf(-a2));
  }
}

__global__ void final_kernel(const float* __restrict__ xres, const float* __restrict__ yc,
                             const float* __restrict__ ss2, const float* __restrict__ avec,
                             float* __restrict__ out) {
  int idx = blockIdx.x * 256 + threadIdx.x;  // 786432
  int c = idx % 96;
  int b = idx / (Ll * 96);
  out[idx] = xres[idx] * ss2[c] + yc[idx] * avec[b * 96 + c];
}

// ---------------- host ----------------
extern "C" void kernel_launch(void* const* d_in, const int* in_sizes, int n_in,
                              void* d_out, int out_size, void* d_ws, size_t ws_size,
                              hipStream_t stream) {
  const float* input      = (const float*)d_in[0];
  const float* ln1_g      = (const float*)d_in[1];
  const float* ln1_b      = (const float*)d_in[2];
  const float* skip_scale = (const float*)d_in[3];
  const float* skip_scale2= (const float*)d_in[4];
  const float* ln2_g      = (const float*)d_in[5];
  const float* ln2_b      = (const float*)d_in[6];
  const float* in_proj_w  = (const float*)d_in[7];
  const float* conv2d_w   = (const float*)d_in[8];
  const float* conv2d_b   = (const float*)d_in[9];
  const float* x_proj_w   = (const float*)d_in[10];
  const float* dt_proj_w  = (const float*)d_in[11];
  const float* dt_proj_b  = (const float*)d_in[12];
  const float* A_logs     = (const float*)d_in[13];
  const float* Ds         = (const float*)d_in[14];
  const float* out_norm_g = (const float*)d_in[15];
  const float* out_norm_b = (const float*)d_in[16];
  const float* out_proj_w = (const float*)d_in[17];
  const float* f1_w       = (const float*)d_in[18];
  const float* f1_b       = (const float*)d_in[19];
  const float* fm_w       = (const float*)d_in[20];
  const float* fm_b       = (const float*)d_in[21];
  const float* f2_w       = (const float*)d_in[22];
  const float* f2_b       = (const float*)d_in[23];
  const float* mg_in_w    = (const float*)d_in[24];
  const float* mg_dw3_w   = (const float*)d_in[25];
  const float* mg_dw5_w   = (const float*)d_in[26];
  const float* mg_out_w   = (const float*)d_in[27];
  const float* ca_w1      = (const float*)d_in[28];
  const float* ca_b1      = (const float*)d_in[29];
  const float* ca_w2      = (const float*)d_in[30];
  const float* ca_b2      = (const float*)d_in[31];

  float* W = (float*)d_ws;   // needs ~115 MB
  float* XN    = W;                     // 786432
  float* ZSILU = XN + 786432;           // 1572864
  float* XX    = ZSILU + 1572864;       // 1572864
  float* XC    = XX + 1572864;          // 1572864
  float* DT    = XC + 1572864;          // 6291456
  float* BSb   = DT + 6291456;          // 524288
  float* CSb   = BSb + 524288;          // 524288
  float* PP    = CSb + 524288;          // 1572864
  float* QQ    = PP + 1572864;          // 1572864
  float* H0    = QQ + 1572864;          // 1572864
  float* OUTY  = H0 + 1572864;          // 6291456
  float* YGATE = OUTY + 6291456;        // 1572864
  float* ATTN  = YGATE + 1572864;       // 786432
  float* FFTOUT= ATTN + 786432;         // 786432
  float* XRES  = FFTOUT + 786432;       // 786432
  float* XN2   = XRES + 786432;         // 786432
  float* MEANS = XN2 + 786432;          // 192
  float* AVEC  = MEANS + 192;           // 192
  // FFT scratch overlays PP/QQ (dead after scanB; FFT chain runs after scanB)
  float* XF  = PP;                      // 393216
  float* TR  = XF + 393216;             // 202752
  float* TI  = TR + 202752;
  float* GR  = TI + 202752;
  float* GI  = GR + 202752;
  float* MR  = TR;                      // reuse (TR/TI dead after dft_col)
  float* MI  = TI;
  float* G2R = GR;                      // reuse (GR/GI dead after fmix)
  float* G2I = GI;
  float* YSP = GI + 202752;             // 393216
  // MGCB overlays DT region (dead after scanC)
  float* PMG = DT;                      // 3145728
  float* YMG = DT + 3145728;            // 1572864
  float* YCb = YMG + 1572864;           // 786432

  // 1) LN1
  ln1_kernel<<<2048, 256, 0, stream>>>(input, ln1_g, ln1_b, XN);
  // 2) in_proj -> xx, silu(z)
  conv1x1_kernel<96, 384, 0, 2, 0, 0><<<512, 256, 0, stream>>>(XN, in_proj_w, nullptr, XX, ZSILU);
  // 3) dwconv3x3 + bias + silu
  dwconv3_silu_kernel<<<6144, 256, 0, stream>>>(XX, conv2d_w, conv2d_b, XC);
  // 4) x_proj/dt_proj/softplus
  proj_kernel<<<512, 256, 0, stream>>>(XC, x_proj_w, dt_proj_w, dt_proj_b, BSb, CSb, DT);
  // 5-6) scan passes A, B
  scanA_kernel<<<1536, 256, 0, stream>>>(DT, XC, BSb, A_logs, PP, QQ);
  scanB_kernel<<<96, 256, 0, stream>>>(PP, QQ, H0);
  // FFT branch (after scanB so it may overlay PP/QQ)
  conv1x1_kernel<96, 48, 0, 1, 1, 1><<<512, 256, 0, stream>>>(XN, f1_w, f1_b, XF, nullptr);
  dft_row_kernel<<<6144, 64, 0, stream>>>(XF, TR, TI);
  dft_col_kernel<<<3168, 64, 0, stream>>>(TR, TI, GR, GI);
  fmix_kernel<<<4224, 128, 0, stream>>>(GR, GI, fm_w, fm_b, MR, MI);
  idft_col_kernel<<<3168, 64, 0, stream>>>(MR, MI, G2R, G2I);
  irfft_row_kernel<<<6144, 64, 0, stream>>>(G2R, G2I, YSP);
  conv1x1_kernel<48, 96, 1, 0, 0, 1><<<512, 256, 0, stream>>>(YSP, f2_w, f2_b, FFTOUT, nullptr);
  // 7) scan pass C
  scanC_kernel<<<1536, 256, 0, stream>>>(DT, XC, BSb, CSb, A_logs, Ds, H0, OUTY);
  // 8) combine dirs + out_norm + gate
  ycomb_kernel<<<2048, 256, 0, stream>>>(OUTY, ZSILU, out_norm_g, out_norm_b, YGATE);
  // 9) out_proj
  conv1x1_kernel<192, 96, 0, 0, 0, 0><<<512, 256, 0, stream>>>(YGATE, out_proj_w, nullptr, ATTN, nullptr);
  // 10) residual + LN2
  resln_kernel<<<2048, 256, 0, stream>>>(input, ATTN, FFTOUT, skip_scale, ln2_g, ln2_b, XRES, XN2);
  // MGCB
  conv1x1_kernel<96, 384, 0, 0, 0, 0><<<512, 256, 0, stream>>>(XN2, mg_in_w, nullptr, PMG, nullptr);
  mgcb_dw_kernel<<<6144, 256, 0, stream>>>(PMG, mg_dw3_w, mg_dw5_w, YMG);
  conv1x1_kernel<192, 96, 0, 0, 0, 0><<<512, 256, 0, stream>>>(YMG, mg_out_w, nullptr, YCb, nullptr);
  camean_kernel<<<192, 256, 0, stream>>>(YCb, MEANS);
  camlp_kernel<<<1, 128, 0, stream>>>(MEANS, ca_w1, ca_b1, ca_w2, ca_b2, AVEC);
  final_kernel<<<3072, 256, 0, stream>>>(XRES, YCb, skip_scale2, AVEC, (float*)d_out);
}

// Round 3
// 474.250 us; speedup vs baseline: 1.1774x; 1.0588x over previous
//
#include <hip/hip_runtime.h>
#include <math.h>

#define DEV __device__ __forceinline__

constexpr int DI = 192, Nn = 16, Rr = 6;
constexpr int Cc = 96;
constexpr int Ll = 4096;           // 64*64
constexpr int NC = 64;             // scan chunks of 64 steps

DEV float silu_(float x) { return x / (1.f + __expf(-x)); }
DEV float wsum64(float v) {
  #pragma unroll
  for (int m = 32; m; m >>= 1) v += __shfl_xor(v, m, 64);
  return v;
}
// quad (4-lane) butterfly adds via DPP quad_perm — VALU pipe, no LDS
DEV float qadd1(float v) {
  int i = __builtin_amdgcn_mov_dpp(__float_as_int(v), 0xB1, 0xF, 0xF, true); // [1,0,3,2]
  return v + __int_as_float(i);
}
DEV float qadd2(float v) {
  int i = __builtin_amdgcn_mov_dpp(__float_as_int(v), 0x4E, 0xF, 0xF, true); // [2,3,0,1]
  return v + __int_as_float(i);
}

// ---------------- LN over C=96 (wave per pixel) ----------------
__global__ void ln1_kernel(const float* __restrict__ x, const float* __restrict__ g,
                           const float* __restrict__ bt, float* __restrict__ xn) {
  int lane = threadIdx.x & 63;
  int pix = blockIdx.x * 4 + (threadIdx.x >> 6);
  const float* row = x + (size_t)pix * Cc;
  float v0 = row[lane];
  float v1 = (lane < 32) ? row[lane + 64] : 0.f;
  float s = wsum64(v0 + v1);
  float m = s * (1.f / 96.f);
  float q = wsum64(v0 * v0 + v1 * v1);
  float rs = rsqrtf(q * (1.f / 96.f) - m * m + 1e-6f);
  float* o = xn + (size_t)pix * Cc;
  o[lane] = (v0 - m) * rs * g[lane] + bt[lane];
  if (lane < 32) o[lane + 64] = (v1 - m) * rs * g[lane + 64] + bt[lane + 64];
}

// ---------------- register-tiled 1x1 conv (fp32 micro-GEMM) ----------------
// Block: PXB pixels × CB output channels. Thread: PXT=PXB/16 pixels × CCN=CB/16 outs.
// x staged in LDS as float4 rows with odd unit stride (conflict-free b128 reads).
// IN_MODE: 0 = pixel-major [gp*CIN+c], 1 = channel-major [(b*CIN+c)*4096+p]
// OUT_MODE: 0 = pixel-major, 2 = split xz (c<192 -> out raw, else out2 silu)
template<int CIN, int COUT, int CB, int PXB, int IN_MODE, int OUT_MODE, int ACT, int HAS_BIAS>
__global__ void conv1x1v2_kernel(const float* __restrict__ in, const float* __restrict__ w,
                                 const float* __restrict__ bias, float* __restrict__ out,
                                 float* __restrict__ out2) {
  constexpr int J4 = CIN / 4, STR = J4 + 1, CCN = CB / 16, PXT = PXB / 16;
  constexpr int NPB = 8192 / PXB;
  __shared__ float4 xv[PXB * STR];
  int t = threadIdx.x;
  int pb = blockIdx.x % NPB;
  int cbase = (blockIdx.x / NPB) * CB;
  int pbase = pb * PXB;
  if (IN_MODE == 0) {
    for (int idx = t; idx < PXB * J4; idx += 256) {
      int px = idx / J4, j4 = idx - px * J4;
      xv[px * STR + j4] = ((const float4*)in)[(size_t)(pbase + px) * J4 + j4];
    }
  } else {
    for (int idx = t; idx < PXB * CIN; idx += 256) {
      int px = idx & (PXB - 1), c = idx / PXB;
      int gp = pbase + px; int b = gp >> 12, p = gp & 4095;
      ((float*)xv)[px * (STR * 4) + c] = in[((size_t)b * CIN + c) * Ll + p];
    }
  }
  __syncthreads();
  int g = t >> 4, ci = t & 15;
  float acc[PXT][CCN];
  #pragma unroll
  for (int cc = 0; cc < CCN; ++cc) {
    float b0 = HAS_BIAS ? bias[cbase + ci + 16 * cc] : 0.f;
    #pragma unroll
    for (int p = 0; p < PXT; ++p) acc[p][cc] = b0;
  }
  #pragma unroll 2
  for (int j4 = 0; j4 < J4; ++j4) {
    float4 xr[PXT];
    #pragma unroll
    for (int p = 0; p < PXT; ++p) xr[p] = xv[(g + 16 * p) * STR + j4];
    #pragma unroll
    for (int cc = 0; cc < CCN; ++cc) {
      float4 w4 = ((const float4*)w)[(size_t)(cbase + ci + 16 * cc) * J4 + j4];
      #pragma unroll
      for (int p = 0; p < PXT; ++p)
        acc[p][cc] += xr[p].x * w4.x + xr[p].y * w4.y + xr[p].z * w4.z + xr[p].w * w4.w;
    }
  }
  #pragma unroll
  for (int p = 0; p < PXT; ++p) {
    int gp = pbase + g + 16 * p;
    #pragma unroll
    for (int cc = 0; cc < CCN; ++cc) {
      int c = cbase + ci + 16 * cc;
      float v = acc[p][cc];
      if (OUT_MODE == 2) {
        if (c < 192) out[(size_t)gp * 192 + c] = v;
        else out2[(size_t)gp * 192 + (c - 192)] = silu_(v);
      } else {
        if (ACT == 1) v = silu_(v);
        out[(size_t)gp * COUT + c] = v;
      }
    }
  }
}

// ---------------- depthwise 3x3 + bias + silu (NHWC, 192 ch) ----------------
__global__ void dwconv3_silu_kernel(const float* __restrict__ xx, const float* __restrict__ w,
                                    const float* __restrict__ bias, float* __restrict__ xc) {
  int idx = blockIdx.x * 256 + threadIdx.x;   // (b*L+p)*DI + d
  int d = idx % DI;
  int p = (idx / DI) & (Ll - 1);
  int b = idx / (DI * Ll);
  int h = p >> 6, wq = p & 63;
  const float* base = xx + (size_t)b * Ll * DI + d;
  const float* wr = w + d * 9;
  float acc = bias[d];
  #pragma unroll
  for (int i = 0; i < 3; ++i) {
    int hh = h - 1 + i;
    if ((unsigned)hh >= 64u) continue;
    #pragma unroll
    for (int j = 0; j < 3; ++j) {
      int ww2 = wq - 1 + j;
      if ((unsigned)ww2 >= 64u) continue;
      acc += base[(size_t)(hh * 64 + ww2) * DI] * wr[i * 3 + j];
    }
  }
  xc[idx] = silu_(acc);
}

// ---------------- x_proj + dt_proj + softplus, register-tiled ----------------
__global__ void proj_kernel(const float* __restrict__ xc, const float* __restrict__ xpw,
                            const float* __restrict__ dtw, const float* __restrict__ dtb,
                            float* __restrict__ BSo, float* __restrict__ CSo,
                            float* __restrict__ DTo) {
  __shared__ float4 xv[64 * 49];
  __shared__ float dts[64][13];
  int t = threadIdx.x;
  int lb = (blockIdx.x & 63) * 64;
  int k = (blockIdx.x >> 6) & 3;
  int b = blockIdx.x >> 8;
  int bk = b * 4 + k;
  // stage 64 permuted pixel rows (float4, coalesced)
  for (int idx = t; idx < 64 * 48; idx += 256) {
    int it = idx / 48, j4 = idx - it * 48;
    int l = lb + it, p;
    if (k == 0) p = l;
    else if (k == 1) p = ((l & 63) << 6) | (l >> 6);
    else if (k == 2) p = 4095 - l;
    else { int lr = 4095 - l; p = ((lr & 63) << 6) | (lr >> 6); }
    xv[it * 49 + j4] = ((const float4*)(xc + ((size_t)b * Ll + p) * DI))[j4];
  }
  __syncthreads();
  // x_proj: 38 outputs per pixel, tiled 4px x 3c per thread
  int g = t >> 4, ci = t & 15;
  float acc[4][3];
  #pragma unroll
  for (int p = 0; p < 4; ++p)
    #pragma unroll
    for (int cc = 0; cc < 3; ++cc) acc[p][cc] = 0.f;
  #pragma unroll 2
  for (int j4 = 0; j4 < 48; ++j4) {
    float4 xr[4];
    #pragma unroll
    for (int p = 0; p < 4; ++p) xr[p] = xv[(g + 16 * p) * 49 + j4];
    #pragma unroll
    for (int cc = 0; cc < 3; ++cc) {
      int c = ci + 16 * cc;
      if (c < 38) {
        float4 w4 = ((const float4*)xpw)[(size_t)(k * 38 + c) * 48 + j4];
        #pragma unroll
        for (int p = 0; p < 4; ++p)
          acc[p][cc] += xr[p].x * w4.x + xr[p].y * w4.y + xr[p].z * w4.z + xr[p].w * w4.w;
      }
    }
  }
  #pragma unroll
  for (int p = 0; p < 4; ++p) {
    int px = g + 16 * p;
    int l = lb + px;
    #pragma unroll
    for (int cc = 0; cc < 3; ++cc) {
      int c = ci + 16 * cc;
      if (c < 6) dts[px][c] = acc[p][cc];
      else if (c < 22) BSo[((size_t)bk * Ll + l) * Nn + (c - 6)] = acc[p][cc];
      else if (c < 38) CSo[((size_t)bk * Ll + l) * Nn + (c - 22)] = acc[p][cc];
    }
  }
  __syncthreads();
  // dt_proj + softplus (coalesced store in l)
  int i = t & 63, wv = t >> 6;
  int l = lb + i;
  float r0 = dts[i][0], r1 = dts[i][1], r2 = dts[i][2];
  float r3 = dts[i][3], r4 = dts[i][4], r5 = dts[i][5];
  for (int d = wv; d < DI; d += 4) {
    const float* wr = dtw + ((size_t)k * DI + d) * Rr;
    float a = dtb[k * DI + d] + r0 * wr[0] + r1 * wr[1] + r2 * wr[2]
            + r3 * wr[3] + r4 * wr[4] + r5 * wr[5];
    float sp = (a > 20.f) ? a : log1pf(__expf(a));
    DTo[((size_t)bk * DI + d) * Ll + l] = sp;
  }
}

// ---------------- scan helpers: direction start/stride within chunk ----------------
DEV void dir_p0_dp(int k, int c, int& p0, int& dp) {
  if (k == 0) { p0 = c * 64; dp = 1; }
  else if (k == 1) { p0 = c; dp = 64; }
  else if (k == 2) { p0 = 4095 - c * 64; dp = -1; }
  else { p0 = 4095 - c; dp = -64; }
}

// ---------------- scan pass A: per-chunk (prod a, partial), 4 n-states/thread ----------------
__global__ void scanA_kernel(const float* __restrict__ dtg, const float* __restrict__ xc,
                             const float* __restrict__ bsg, const float* __restrict__ alog,
                             float* __restrict__ P, float* __restrict__ Q) {
  int g = blockIdx.x * 256 + threadIdx.x;   // ((bk*64+c)*192+d)*4+ng
  int ng = g & 3;
  int t1 = g >> 2;
  int d = t1 % DI;
  int t2 = t1 / DI;
  int c = t2 & 63;
  int bk = t2 >> 6;
  int k = bk & 3, b = bk >> 2;
  float4 al = ((const float4*)alog)[(size_t)(k * DI + d) * 4 + ng];
  float An0 = -__expf(al.x), An1 = -__expf(al.y), An2 = -__expf(al.z), An3 = -__expf(al.w);
  const float* dtp = dtg + ((size_t)bk * DI + d) * Ll + c * 64;
  const float4* bsp = (const float4*)bsg + ((size_t)bk * Ll + c * 64) * 4 + ng;
  int p0, dp; dir_p0_dp(k, c, p0, dp);
  const float* up = xc + ((size_t)b * Ll + p0) * DI + d;
  int ustep = dp * DI;
  float P0 = 1.f, P1 = 1.f, P2 = 1.f, P3 = 1.f;
  float Q0 = 0.f, Q1 = 0.f, Q2 = 0.f, Q3 = 0.f;
  #pragma unroll 4
  for (int t = 0; t < 64; ++t) {
    float dtv = dtp[t];
    float u = *up; up += ustep;
    float4 Bv = *bsp; bsp += 4;
    float s = dtv * u;
    float a0 = __expf(dtv * An0), a1 = __expf(dtv * An1);
    float a2 = __expf(dtv * An2), a3 = __expf(dtv * An3);
    P0 *= a0; P1 *= a1; P2 *= a2; P3 *= a3;
    Q0 = Q0 * a0 + s * Bv.x; Q1 = Q1 * a1 + s * Bv.y;
    Q2 = Q2 * a2 + s * Bv.z; Q3 = Q3 * a3 + s * Bv.w;
  }
  ((float4*)P)[g] = make_float4(P0, P1, P2, P3);
  ((float4*)Q)[g] = make_float4(Q0, Q1, Q2, Q3);
}

// ---------------- scan pass B: cross-chunk prefix ----------------
__global__ void scanB_kernel(const float* __restrict__ P, const float* __restrict__ Q,
                             float* __restrict__ H0) {
  int g = blockIdx.x * 256 + threadIdx.x;   // (bk*192+d)*16+n, 24576
  int n = g & 15;
  int d = (g >> 4) % DI;
  int bk = (g >> 4) / DI;
  float h = 0.f;
  for (int c = 0; c < NC; ++c) {
    size_t idx = (((size_t)bk * NC + c) * DI + d) * Nn + n;
    H0[idx] = h;
    h = P[idx] * h + Q[idx];
  }
}

// ---------------- scan pass C: replay + y emit (+ xs*Ds), 4 n-states/thread ----------------
__global__ void scanC_kernel(const float* __restrict__ dtg, const float* __restrict__ xc,
                             const float* __restrict__ bsg, const float* __restrict__ csg,
                             const float* __restrict__ alog, const float* __restrict__ Dsv_,
                             const float* __restrict__ H0, float* __restrict__ outy) {
  int g = blockIdx.x * 256 + threadIdx.x;
  int ng = g & 3;
  int t1 = g >> 2;
  int d = t1 % DI;
  int t2 = t1 / DI;
  int c = t2 & 63;
  int bk = t2 >> 6;
  int k = bk & 3, b = bk >> 2;
  float4 al = ((const float4*)alog)[(size_t)(k * DI + d) * 4 + ng];
  float An0 = -__expf(al.x), An1 = -__expf(al.y), An2 = -__expf(al.z), An3 = -__expf(al.w);
  float Dsv = Dsv_[k * DI + d];
  const float* dtp = dtg + ((size_t)bk * DI + d) * Ll + c * 64;
  const float4* bsp = (const float4*)bsg + ((size_t)bk * Ll + c * 64) * 4 + ng;
  const float4* csp = (const float4*)csg + ((size_t)bk * Ll + c * 64) * 4 + ng;
  int p0, dp; dir_p0_dp(k, c, p0, dp);
  const float* up = xc + ((size_t)b * Ll + p0) * DI + d;
  int ustep = dp * DI;
  float* yo = outy + ((size_t)bk * Ll + c * 64) * DI + d;
  float4 h4 = ((const float4*)H0)[g];
  float h0 = h4.x, h1 = h4.y, h2 = h4.z, h3 = h4.w;
  #pragma unroll 4
  for (int t = 0; t < 64; ++t) {
    float dtv = dtp[t];
    float u = *up; up += ustep;
    float4 Bv = *bsp; bsp += 4;
    float4 Cv = *csp; csp += 4;
    float s = dtv * u;
    float a0 = __expf(dtv * An0), a1 = __expf(dtv * An1);
    float a2 = __expf(dtv * An2), a3 = __expf(dtv * An3);
    h0 = h0 * a0 + s * Bv.x; h1 = h1 * a1 + s * Bv.y;
    h2 = h2 * a2 + s * Bv.z; h3 = h3 * a3 + s * Bv.w;
    float yp = h0 * Cv.x + h1 * Cv.y + h2 * Cv.z + h3 * Cv.w;
    yp = qadd1(yp);
    yp = qadd2(yp);
    if (ng == 0) yo[(size_t)t * DI] = yp + u * Dsv;
  }
}

// ---------------- combine 4 dirs + out_norm LN + silu(z) gate ----------------
__global__ void ycomb_kernel(const float* __restrict__ outy, const float* __restrict__ zs,
                             const float* __restrict__ g, const float* __restrict__ bt,
                             float* __restrict__ ygate) {
  int lane = threadIdx.x & 63;
  int pix = blockIdx.x * 4 + (threadIdx.x >> 6);
  int p = pix & 4095, b = pix >> 12;
  int l1 = ((p & 63) << 6) | (p >> 6);
  size_t base = (size_t)b * 4 * Ll * DI;
  const float* y0 = outy + base + (size_t)p * DI;
  const float* y2 = outy + base + ((size_t)2 * Ll + (4095 - p)) * DI;
  const float* y1 = outy + base + ((size_t)1 * Ll + l1) * DI;
  const float* y3 = outy + base + ((size_t)3 * Ll + (4095 - l1)) * DI;
  float v[3];
  #pragma unroll
  for (int j = 0; j < 3; ++j) {
    int d = lane + j * 64;
    v[j] = y0[d] + y2[d] + y1[d] + y3[d];
  }
  float s = wsum64(v[0] + v[1] + v[2]);
  float m = s * (1.f / 192.f);
  float q = wsum64(v[0] * v[0] + v[1] * v[1] + v[2] * v[2]);
  float rs = rsqrtf(q * (1.f / 192.f) - m * m + 1e-5f);
  const float* zrow = zs + (size_t)pix * DI;
  float* orow = ygate + (size_t)pix * DI;
  #pragma unroll
  for (int j = 0; j < 3; ++j) {
    int d = lane + j * 64;
    float yn = (v[j] - m) * rs * g[d] + bt[d];
    orow[d] = yn * zrow[d];
  }
}

// ---------------- residual + LN2 ----------------
__global__ void resln_kernel(const float* __restrict__ x4, const float* __restrict__ attn,
                             const float* __restrict__ fft, const float* __restrict__ ss,
                             const float* __restrict__ g, const float* __restrict__ bt,
                             float* __restrict__ xres, float* __restrict__ xn2) {
  int lane = threadIdx.x & 63;
  int pix = blockIdx.x * 4 + (threadIdx.x >> 6);
  size_t o = (size_t)pix * Cc;
  float v0 = x4[o + lane] * ss[lane] + attn[o + lane] + fft[o + lane];
  float v1 = 0.f;
  if (lane < 32) v1 = x4[o + lane + 64] * ss[lane + 64] + attn[o + lane + 64] + fft[o + lane + 64];
  float s = wsum64(v0 + v1);
  float m = s * (1.f / 96.f);
  float q = wsum64(v0 * v0 + v1 * v1);
  float rs = rsqrtf(q * (1.f / 96.f) - m * m + 1e-5f);
  xres[o + lane] = v0;
  xn2[o + lane] = (v0 - m) * rs * g[lane] + bt[lane];
  if (lane < 32) {
    xres[o + lane + 64] = v1;
    xn2[o + lane + 64] = (v1 - m) * rs * g[lane + 64] + bt[lane + 64];
  }
}

// ---------------- FFT branch: 64-point DFTs via twiddle table ----------------
// xf is pixel-major [b][p][48]
__global__ void dft_row_kernel(const float* __restrict__ xf, float* __restrict__ Tr,
                               float* __restrict__ Ti) {
  __shared__ float row[64], cs[64], sn[64];
  int lane = threadIdx.x;
  int bch = blockIdx.x;  // (b*48+c)*64 + h
  int h = bch & 63;
  int bc = bch >> 6;
  int c = bc % 48, b = bc / 48;
  row[lane] = xf[((size_t)b * Ll + h * 64 + lane) * 48 + c];
  float ang = (float)((double)lane * (2.0 * 3.14159265358979323846 / 64.0));
  float s0, c0; sincosf(ang, &s0, &c0); sn[lane] = s0; cs[lane] = c0;
  __syncthreads();
  if (lane < 33) {
    float ar = 0.f, ai = 0.f;
    for (int wq = 0; wq < 64; ++wq) {
      int j = (lane * wq) & 63;
      ar += row[wq] * cs[j];
      ai -= row[wq] * sn[j];
    }
    Tr[(size_t)bch * 33 + lane] = ar;
    Ti[(size_t)bch * 33 + lane] = ai;
  }
}

__global__ void dft_col_kernel(const float* __restrict__ Tr, const float* __restrict__ Ti,
                               float* __restrict__ Gr, float* __restrict__ Gi) {
  __shared__ float tr[64], ti[64], cs[64], sn[64];
  int lane = threadIdx.x;  // = u
  int v = blockIdx.x % 33, bc = blockIdx.x / 33;
  tr[lane] = Tr[((size_t)bc * 64 + lane) * 33 + v];
  ti[lane] = Ti[((size_t)bc * 64 + lane) * 33 + v];
  float ang = (float)((double)lane * (2.0 * 3.14159265358979323846 / 64.0));
  float s0, c0; sincosf(ang, &s0, &c0); sn[lane] = s0; cs[lane] = c0;
  __syncthreads();
  float ar = 0.f, ai = 0.f;
  for (int hh = 0; hh < 64; ++hh) {
    int j = (lane * hh) & 63;
    ar += tr[hh] * cs[j] + ti[hh] * sn[j];
    ai += ti[hh] * cs[j] - tr[hh] * sn[j];
  }
  Gr[((size_t)bc * 64 + lane) * 33 + v] = ar * (1.f / 64.f);
  Gi[((size_t)bc * 64 + lane) * 33 + v] = ai * (1.f / 64.f);
}

__global__ void fmix_kernel(const float* __restrict__ Gr, const float* __restrict__ Gi,
                            const float* __restrict__ w, const float* __restrict__ bias,
                            float* __restrict__ Mr, float* __restrict__ Mi) {
  __shared__ float fin[96];
  int tid = threadIdx.x;
  int b = blockIdx.x / 2112, uv = blockIdx.x % 2112;
  if (tid < 96) {
    size_t src = ((size_t)(b * 48 + (tid >> 1))) * 2112 + uv;
    fin[tid] = (tid & 1) ? Gi[src] : Gr[src];
  }
  __syncthreads();
  if (tid < 96) {
    float acc = bias[tid];
    const float* wr = w + tid * 96;
    #pragma unroll 8
    for (int ci = 0; ci < 96; ++ci) acc += fin[ci] * wr[ci];
    acc = silu_(acc);
    size_t dst = ((size_t)(b * 48 + (tid >> 1))) * 2112 + uv;
    if (tid & 1) Mi[dst] = acc; else Mr[dst] = acc;
  }
}

__global__ void idft_col_kernel(const float* __restrict__ Mr, const float* __restrict__ Mi,
                                float* __restrict__ gr, float* __restrict__ gi) {
  __shared__ float mr[64], mi[64], cs[64], sn[64];
  int lane = threadIdx.x;  // = h
  int v = blockIdx.x % 33, bc = blockIdx.x / 33;
  mr[lane] = Mr[((size_t)bc * 64 + lane) * 33 + v];
  mi[lane] = Mi[((size_t)bc * 64 + lane) * 33 + v];
  float ang = (float)((double)lane * (2.0 * 3.14159265358979323846 / 64.0));
  float s0, c0; sincosf(ang, &s0, &c0); sn[lane] = s0; cs[lane] = c0;
  __syncthreads();
  float ar = 0.f, ai = 0.f;
  for (int u = 0; u < 64; ++u) {
    int j = (lane * u) & 63;
    ar += mr[u] * cs[j] - mi[u] * sn[j];
    ai += mr[u] * sn[j] + mi[u] * cs[j];
  }
  gr[((size_t)bc * 64 + lane) * 33 + v] = ar;
  gi[((size_t)bc * 64 + lane) * 33 + v] = ai;
}

__global__ void irfft_row_kernel(const float* __restrict__ gr, const float* __restrict__ gi,
                                 float* __restrict__ ysp) {
  __shared__ float r[33], im[33], cs[64], sn[64];
  int lane = threadIdx.x;  // = w
  int bch = blockIdx.x;    // (b*48+c)*64 + h
  if (lane < 33) { r[lane] = gr[(size_t)bch * 33 + lane]; im[lane] = gi[(size_t)bch * 33 + lane]; }
  float ang = (float)((double)lane * (2.0 * 3.14159265358979323846 / 64.0));
  float s0, c0; sincosf(ang, &s0, &c0); sn[lane] = s0; cs[lane] = c0;
  __syncthreads();
  float acc = r[0] + ((lane & 1) ? -r[32] : r[32]);
  for (int v = 1; v < 32; ++v) {
    int j = (v * lane) & 63;
    acc += 2.f * (r[v] * cs[j] - im[v] * sn[j]);
  }
  ysp[(size_t)bch * 64 + lane] = acc * (1.f / 64.f);
}

// ---------------- MGCB depthwise + gelu gate ----------------
__global__ void mgcb_dw_kernel(const float* __restrict__ pm, const float* __restrict__ w3,
                               const float* __restrict__ w5, float* __restrict__ ymg) {
  int idx = blockIdx.x * 256 + threadIdx.x;  // (b*L+p)*192 + cc
  int cc = idx % DI;
  int p = (idx / DI) & (Ll - 1);
  int b = idx / (DI * Ll);
  int h = p >> 6, wq = p & 63;
  const float* base = pm + (size_t)b * Ll * 384;
  const float* wr = w3 + cc * 9;
  float gg = 0.f;
  #pragma unroll
  for (int i = 0; i < 3; ++i) {
    int hh = h - 1 + i; if ((unsigned)hh >= 64u) continue;
    #pragma unroll
    for (int j = 0; j < 3; ++j) {
      int ww2 = wq - 1 + j; if ((unsigned)ww2 >= 64u) continue;
      gg += base[(size_t)(hh * 64 + ww2) * 384 + cc] * wr[i * 3 + j];
    }
  }
  float mm = 0.f;
  if (cc < 96) {
    int c2 = 192 + cc;
    const float* wr2 = w3 + c2 * 9;
    #pragma unroll
    for (int i = 0; i < 3; ++i) {
      int hh = h - 1 + i; if ((unsigned)hh >= 64u) continue;
      #pragma unroll
      for (int j = 0; j < 3; ++j) {
        int ww2 = wq - 1 + j; if ((unsigned)ww2 >= 64u) continue;
        mm += base[(size_t)(hh * 64 + ww2) * 384 + c2] * wr2[i * 3 + j];
      }
    }
  } else {
    int c5 = 288 + (cc - 96);
    const float* wr5 = w5 + (cc - 96) * 25;
    #pragma unroll
    for (int i = 0; i < 5; ++i) {
      int hh = h - 2 + i; if ((unsigned)hh >= 64u) continue;
      #pragma unroll
      for (int j = 0; j < 5; ++j) {
        int ww2 = wq - 2 + j; if ((unsigned)ww2 >= 64u) continue;
        mm += base[(size_t)(hh * 64 + ww2) * 384 + c5] * wr5[i * 5 + j];
      }
    }
  }
  float ge = 0.5f * gg * (1.f + erff(gg * 0.70710678118654752f));
  ymg[idx] = ge * mm;
}

// ---------------- channel attention ----------------
__global__ void camean_kernel(const float* __restrict__ yc, float* __restrict__ means) {
  __shared__ float red[256];
  int c = blockIdx.x % 96, b = blockIdx.x / 96;
  float s = 0.f;
  for (int p = threadIdx.x; p < Ll; p += 256) s += yc[((size_t)b * Ll + p) * Cc + c];
  red[threadIdx.x] = s; __syncthreads();
  for (int st = 128; st > 0; st >>= 1) {
    if (threadIdx.x < st) red[threadIdx.x] += red[threadIdx.x + st];
    __syncthreads();
  }
  if (threadIdx.x == 0) means[b * 96 + c] = red[0] * (1.f / 4096.f);
}

__global__ void camlp_kernel(const float* __restrict__ means, const float* __restrict__ w1,
                             const float* __restrict__ b1, const float* __restrict__ w2,
                             const float* __restrict__ b2, float* __restrict__ avec) {
  int c = threadIdx.x;
  if (c >= 96) return;
  for (int b = 0; b < 2; ++b) {
    float t[3];
    #pragma unroll
    for (int j = 0; j < 3; ++j) {
      float a = b1[j];
      for (int cc = 0; cc < 96; ++cc) a += means[b * 96 + cc] * w1[j * 96 + cc];
      t[j] = fmaxf(a, 0.f);
    }
    float a2 = b2[c];
    #pragma unroll
    for (int j = 0; j < 3; ++j) a2 += t[j] * w2[c * 3 + j];
    avec[b * 96 + c] = 1.f / (1.f + expf(-a2));
  }
}

__global__ void final_kernel(const float* __restrict__ xres, const float* __restrict__ yc,
                             const float* __restrict__ ss2, const float* __restrict__ avec,
                             float* __restrict__ out) {
  int idx = blockIdx.x * 256 + threadIdx.x;  // 786432
  int c = idx % 96;
  int b = idx / (Ll * 96);
  out[idx] = xres[idx] * ss2[c] + yc[idx] * avec[b * 96 + c];
}

// ---------------- host ----------------
extern "C" void kernel_launch(void* const* d_in, const int* in_sizes, int n_in,
                              void* d_out, int out_size, void* d_ws, size_t ws_size,
                              hipStream_t stream) {
  const float* input      = (const float*)d_in[0];
  const float* ln1_g      = (const float*)d_in[1];
  const float* ln1_b      = (const float*)d_in[2];
  const float* skip_scale = (const float*)d_in[3];
  const float* skip_scale2= (const float*)d_in[4];
  const float* ln2_g      = (const float*)d_in[5];
  const float* ln2_b      = (const float*)d_in[6];
  const float* in_proj_w  = (const float*)d_in[7];
  const float* conv2d_w   = (const float*)d_in[8];
  const float* conv2d_b   = (const float*)d_in[9];
  const float* x_proj_w   = (const float*)d_in[10];
  const float* dt_proj_w  = (const float*)d_in[11];
  const float* dt_proj_b  = (const float*)d_in[12];
  const float* A_logs     = (const float*)d_in[13];
  const float* Ds         = (const float*)d_in[14];
  const float* out_norm_g = (const float*)d_in[15];
  const float* out_norm_b = (const float*)d_in[16];
  const float* out_proj_w = (const float*)d_in[17];
  const float* f1_w       = (const float*)d_in[18];
  const float* f1_b       = (const float*)d_in[19];
  const float* fm_w       = (const float*)d_in[20];
  const float* fm_b       = (const float*)d_in[21];
  const float* f2_w       = (const float*)d_in[22];
  const float* f2_b       = (const float*)d_in[23];
  const float* mg_in_w    = (const float*)d_in[24];
  const float* mg_dw3_w   = (const float*)d_in[25];
  const float* mg_dw5_w   = (const float*)d_in[26];
  const float* mg_out_w   = (const float*)d_in[27];
  const float* ca_w1      = (const float*)d_in[28];
  const float* ca_b1      = (const float*)d_in[29];
  const float* ca_w2      = (const float*)d_in[30];
  const float* ca_b2      = (const float*)d_in[31];

  float* W = (float*)d_ws;   // needs ~115 MB
  float* XN    = W;                     // 786432
  float* ZSILU = XN + 786432;           // 1572864
  float* XX    = ZSILU + 1572864;       // 1572864
  float* XC    = XX + 1572864;          // 1572864
  float* DT    = XC + 1572864;          // 6291456
  float* BSb   = DT + 6291456;          // 524288
  float* CSb   = BSb + 524288;          // 524288
  float* PP    = CSb + 524288;          // 1572864
  float* QQ    = PP + 1572864;          // 1572864
  float* H0    = QQ + 1572864;          // 1572864
  float* OUTY  = H0 + 1572864;          // 6291456
  float* YGATE = OUTY + 6291456;        // 1572864
  float* ATTN  = YGATE + 1572864;       // 786432
  float* FFTOUT= ATTN + 786432;         // 786432
  float* XRES  = FFTOUT + 786432;       // 786432
  float* XN2   = XRES + 786432;         // 786432
  float* MEANS = XN2 + 786432;          // 192
  float* AVEC  = MEANS + 192;           // 192
  // FFT scratch overlays PP/QQ (dead after scanB; FFT chain runs after scanB)
  float* XF  = PP;                      // 393216 (pixel-major [b][p][48])
  float* TR  = XF + 393216;             // 202752
  float* TI  = TR + 202752;
  float* GR  = TI + 202752;
  float* GI  = GR + 202752;
  float* MR  = TR;                      // reuse (TR/TI dead after dft_col)
  float* MI  = TI;
  float* G2R = GR;                      // reuse (GR/GI dead after fmix)
  float* G2I = GI;
  float* YSP = GI + 202752;             // 393216
  // MGCB overlays DT region (dead after scanC)
  float* PMG = DT;                      // 3145728
  float* YMG = DT + 3145728;            // 1572864
  float* YCb = YMG + 1572864;           // 786432

  // 1) LN1
  ln1_kernel<<<2048, 256, 0, stream>>>(input, ln1_g, ln1_b, XN);
  // 2) in_proj -> xx, silu(z)   (CIN=96, COUT=384, CB=96, PXB=64, split-c grid 512)
  conv1x1v2_kernel<96, 384, 96, 64, 0, 2, 0, 0><<<512, 256, 0, stream>>>(XN, in_proj_w, nullptr, XX, ZSILU);
  // 3) dwconv3x3 + bias + silu
  dwconv3_silu_kernel<<<6144, 256, 0, stream>>>(XX, conv2d_w, conv2d_b, XC);
  // 4) x_proj/dt_proj/softplus
  proj_kernel<<<512, 256, 0, stream>>>(XC, x_proj_w, dt_proj_w, dt_proj_b, BSb, CSb, DT);
  // 5-6) scan passes A, B
  scanA_kernel<<<1536, 256, 0, stream>>>(DT, XC, BSb, A_logs, PP, QQ);
  scanB_kernel<<<96, 256, 0, stream>>>(PP, QQ, H0);
  // FFT branch (after scanB so it may overlay PP/QQ)
  conv1x1v2_kernel<96, 48, 48, 32, 0, 0, 1, 1><<<256, 256, 0, stream>>>(XN, f1_w, f1_b, XF, nullptr);
  dft_row_kernel<<<6144, 64, 0, stream>>>(XF, TR, TI);
  dft_col_kernel<<<3168, 64, 0, stream>>>(TR, TI, GR, GI);
  fmix_kernel<<<4224, 128, 0, stream>>>(GR, GI, fm_w, fm_b, MR, MI);
  idft_col_kernel<<<3168, 64, 0, stream>>>(MR, MI, G2R, G2I);
  irfft_row_kernel<<<6144, 64, 0, stream>>>(G2R, G2I, YSP);
  conv1x1v2_kernel<48, 96, 96, 32, 1, 0, 0, 1><<<256, 256, 0, stream>>>(YSP, f2_w, f2_b, FFTOUT, nullptr);
  // 7) scan pass C
  scanC_kernel<<<1536, 256, 0, stream>>>(DT, XC, BSb, CSb, A_logs, Ds, H0, OUTY);
  // 8) combine dirs + out_norm + gate
  ycomb_kernel<<<2048, 256, 0, stream>>>(OUTY, ZSILU, out_norm_g, out_norm_b, YGATE);
  // 9) out_proj
  conv1x1v2_kernel<192, 96, 96, 32, 0, 0, 0, 0><<<256, 256, 0, stream>>>(YGATE, out_proj_w, nullptr, ATTN, nullptr);
  // 10) residual + LN2
  resln_kernel<<<2048, 256, 0, stream>>>(input, ATTN, FFTOUT, skip_scale, ln2_g, ln2_b, XRES, XN2);
  // MGCB
  conv1x1v2_kernel<96, 384, 96, 64, 0, 0, 0, 0><<<512, 256, 0, stream>>>(XN2, mg_in_w, nullptr, PMG, nullptr);
  mgcb_dw_kernel<<<6144, 256, 0, stream>>>(PMG, mg_dw3_w, mg_dw5_w, YMG);
  conv1x1v2_kernel<192, 96, 96, 32, 0, 0, 0, 0><<<256, 256, 0, stream>>>(YMG, mg_out_w, nullptr, YCb, nullptr);
  camean_kernel<<<192, 256, 0, stream>>>(YCb, MEANS);
  camlp_kernel<<<1, 128, 0, stream>>>(MEANS, ca_w1, ca_b1, ca_w2, ca_b2, AVEC);
  final_kernel<<<3072, 256, 0, stream>>>(XRES, YCb, skip_scale2, AVEC, (float*)d_out);
}